// Round 6
// baseline (564.126 us; speedup 1.0000x reference)
//
#include <hip/hip_runtime.h>
#include <stdint.h>

#define BATCH 4
#define SEQ   2048
#define FDIM  512
#define NHEAD 8
#define HDIM  64
#define KNN   32

typedef unsigned int u32;
typedef unsigned long long u64;
typedef unsigned short u16;

#define SF ((size_t)SEQ * FDIM)          // per-batch tensor elements (1M)

__device__ __forceinline__ u64 shfl_xor_u64(u64 v, int m) {
    int lo = __shfl_xor((int)(u32)v, m, 64);
    int hi = __shfl_xor((int)(u32)(v >> 32), m, 64);
    return (((u64)(u32)hi) << 32) | (u32)lo;
}
__device__ __forceinline__ u64 min_u64(u64 a, u64 b) { return a < b ? a : b; }

// ---------------------------------------------------------------------------
// kNN: one wave per query, fp32 coords. Emulates STABLE argsort of fp32
// distances (self included at rank 0, dropped) — exact jnp.argsort semantics
// incl. duplicate-coordinate ties. Key = (dist_bits<<32)|idx. Output u16.
// ---------------------------------------------------------------------------
__global__ __launch_bounds__(64) void knn_kernel(const float* __restrict__ coords,
                                                 u16* __restrict__ nn_out) {
    __shared__ u64 lists[32 * 64];   // [pos][lane], stride-64
    __shared__ u32 outbuf[KNN + 1];
    const int blk  = blockIdx.x;          // b*SEQ + qi
    const int b    = blk >> 11;
    const int qi   = blk & (SEQ - 1);
    const int lane = threadIdx.x;

    const float* cb = coords + (size_t)b * SEQ * 3;
    const float qx = cb[qi * 3 + 0];
    const float qy = cb[qi * 3 + 1];
    const float qz = cb[qi * 3 + 2];

    u64 key[32];
#pragma unroll
    for (int i = 0; i < 32; ++i) {
        int c = i * 64 + lane;
        float dx = __fsub_rn(cb[c * 3 + 0], qx);
        float dy = __fsub_rn(cb[c * 3 + 1], qy);
        float dz = __fsub_rn(cb[c * 3 + 2], qz);
        // numpy order: (dx*dx + dy*dy) + dz*dz, no FMA contraction, IEEE sqrt
        float d2 = __fadd_rn(__fadd_rn(__fmul_rn(dx, dx), __fmul_rn(dy, dy)),
                             __fmul_rn(dz, dz));
        float dist = __fsqrt_rn(d2);
        key[i] = (((u64)__float_as_uint(dist)) << 32) | (u32)c;   // self included
    }

    // per-lane bitonic sort, ascending, fully unrolled
#pragma unroll
    for (int k = 2; k <= 32; k <<= 1) {
#pragma unroll
        for (int j = k >> 1; j > 0; j >>= 1) {
#pragma unroll
            for (int i = 0; i < 32; ++i) {
                int ixj = i ^ j;
                if (ixj > i) {
                    bool up = (i & k) == 0;
                    u64 a = key[i], c2 = key[ixj];
                    bool sw = up ? (a > c2) : (a < c2);
                    u64 lo = sw ? c2 : a;
                    u64 hi = sw ? a : c2;
                    key[i] = lo;
                    key[ixj] = hi;
                }
            }
        }
    }

#pragma unroll
    for (int i = 0; i < 32; ++i) lists[i * 64 + lane] = key[i];
    __syncthreads();

    u64 h = key[0];
    int ptr = 1;
#pragma unroll 1
    for (int r = 0; r < KNN + 1; ++r) {      // 33 winners; rank 0 = self slot
        u64 g = h;
        g = min_u64(g, shfl_xor_u64(g, 1));
        g = min_u64(g, shfl_xor_u64(g, 2));
        g = min_u64(g, shfl_xor_u64(g, 4));
        g = min_u64(g, shfl_xor_u64(g, 8));
        g = min_u64(g, shfl_xor_u64(g, 16));
        g = min_u64(g, shfl_xor_u64(g, 32));
        if (lane == 0) outbuf[r] = (u32)g;
        if (h == g) {                        // unique winner (idx embedded)
            h = (ptr < 32) ? lists[ptr * 64 + lane] : ~0ull;
            ++ptr;
        }
    }
    __syncthreads();
    if (lane < KNN) nn_out[(size_t)blk * KNN + lane] = (u16)(outbuf[lane + 1] & 0x7FF);
}

// ---------------------------------------------------------------------------
// Projection GEMM: out[m,n] = sum_k x[m,k]*W[n,k]  (x @ W^T), fp32.
// BM=BN=64 BK=16, 256 thr, 4x4 microtile. Rows = gridDim.y*64.
// (Structure validated in round 1: heads 0-3 matched ref.)
// ---------------------------------------------------------------------------
__global__ __launch_bounds__(256) void gemm_xwt(const float* __restrict__ x,
                                                const float* __restrict__ W,
                                                float* __restrict__ out) {
    __shared__ __align__(16) float As[16][68];   // [k][m]
    __shared__ __align__(16) float Bs[16][68];   // [k][n]
    const int m0 = blockIdx.y * 64;
    const int n0 = blockIdx.x * 64;
    const int tid = threadIdx.x;
    const int tx = tid & 15, ty = tid >> 4;
    const int lr = tid >> 2, lq = tid & 3;

    float c[4][4] = {{0.f}};

    for (int k0 = 0; k0 < FDIM; k0 += 16) {
        float4 av = *(const float4*)(x + (size_t)(m0 + lr) * FDIM + k0 + lq * 4);
        float4 bv = *(const float4*)(W + (size_t)(n0 + lr) * FDIM + k0 + lq * 4);
        As[lq * 4 + 0][lr] = av.x; As[lq * 4 + 1][lr] = av.y;
        As[lq * 4 + 2][lr] = av.z; As[lq * 4 + 3][lr] = av.w;
        Bs[lq * 4 + 0][lr] = bv.x; Bs[lq * 4 + 1][lr] = bv.y;
        Bs[lq * 4 + 2][lr] = bv.z; Bs[lq * 4 + 3][lr] = bv.w;
        __syncthreads();
#pragma unroll
        for (int kk = 0; kk < 16; ++kk) {
            float4 a  = *(const float4*)&As[kk][ty * 4];
            float4 bq = *(const float4*)&Bs[kk][tx * 4];
            c[0][0] += a.x * bq.x; c[0][1] += a.x * bq.y; c[0][2] += a.x * bq.z; c[0][3] += a.x * bq.w;
            c[1][0] += a.y * bq.x; c[1][1] += a.y * bq.y; c[1][2] += a.y * bq.z; c[1][3] += a.y * bq.w;
            c[2][0] += a.z * bq.x; c[2][1] += a.z * bq.y; c[2][2] += a.z * bq.z; c[2][3] += a.z * bq.w;
            c[3][0] += a.w * bq.x; c[3][1] += a.w * bq.y; c[3][2] += a.w * bq.z; c[3][3] += a.w * bq.w;
        }
        __syncthreads();
    }
#pragma unroll
    for (int i = 0; i < 4; ++i) {
        float4 v0 = make_float4(c[i][0], c[i][1], c[i][2], c[i][3]);
        *(float4*)(out + (size_t)(m0 + ty * 4 + i) * FDIM + n0 + tx * 4) = v0;
    }
}

// ---------------------------------------------------------------------------
// Attention for ONE batch: block per query, 512 thr = 8 waves, wave per head
// (ALL 8 heads — round-1 bug fixed). kv = [k_b | v_b] fp32 in ws. q read
// from outb (own row, written by q-gemm), then overwritten with the result.
// ---------------------------------------------------------------------------
__global__ __launch_bounds__(512) void attn_kernel(const float* __restrict__ kv,
                                                   const u16* __restrict__ nnb,
                                                   float* __restrict__ outb) {
    __shared__ float qs[FDIM];
    __shared__ int   sidx[KNN];
    __shared__ float wls[NHEAD][KNN];
    const int qi  = blockIdx.x;            // 0..SEQ-1
    const int tid = threadIdx.x;
    const int h = tid >> 6, lane = tid & 63;

    qs[tid] = outb[(size_t)qi * FDIM + tid];                  // own q row
    if (tid < KNN) sidx[tid] = (int)nnb[(size_t)qi * KNN + tid] & (SEQ - 1);
    __syncthreads();

    const int j = lane & 31, half = lane >> 5;
    const float* kreg = kv + (size_t)sidx[j] * FDIM + h * HDIM + half * 32;
    const float* qp = &qs[h * HDIM + half * 32];
    float acc = 0.f;
#pragma unroll
    for (int d = 0; d < 32; d += 4) {
        float4 kvv = *(const float4*)(kreg + d);
        acc += qp[d + 0] * kvv.x + qp[d + 1] * kvv.y
             + qp[d + 2] * kvv.z + qp[d + 3] * kvv.w;
    }
    acc += __shfl_xor(acc, 32, 64);
    float s = acc * 0.125f;                 // 1/sqrt(64)
    float m = s;
    m = fmaxf(m, __shfl_xor(m, 1, 64));
    m = fmaxf(m, __shfl_xor(m, 2, 64));
    m = fmaxf(m, __shfl_xor(m, 4, 64));
    m = fmaxf(m, __shfl_xor(m, 8, 64));
    m = fmaxf(m, __shfl_xor(m, 16, 64));
    float e = __expf(s - m);
    float sum = e;
    sum += __shfl_xor(sum, 1, 64);
    sum += __shfl_xor(sum, 2, 64);
    sum += __shfl_xor(sum, 4, 64);
    sum += __shfl_xor(sum, 8, 64);
    sum += __shfl_xor(sum, 16, 64);
    float w = e / sum;
    if (half == 0) wls[h][j] = w;
    __syncthreads();

    const float* vb = kv + SF + h * HDIM + lane;     // v_b base
    float o = 0.f;
#pragma unroll 4
    for (int j2 = 0; j2 < KNN; ++j2) {
        o += wls[h][j2] * vb[(size_t)sidx[j2] * FDIM];
    }
    outb[(size_t)qi * FDIM + h * HDIM + lane] = o;
}

// ---------------------------------------------------------------------------
// metric = mean_s(k) = (mean_s x) @ Wk^T  (linearity), fp32
// ---------------------------------------------------------------------------
__global__ __launch_bounds__(256) void xbar_kernel(const float* __restrict__ x,
                                                   float* __restrict__ xbar) {
    const int b = blockIdx.x, chunk = blockIdx.y;   // 32 chunks of 64 rows
    const int tid = threadIdx.x;
    const float* xp = x + (size_t)b * SF + (size_t)chunk * 64 * FDIM;
    float s0 = 0.f, s1 = 0.f;
    for (int r = 0; r < 64; ++r) {
        s0 += xp[(size_t)r * FDIM + tid];
        s1 += xp[(size_t)r * FDIM + tid + 256];
    }
    atomicAdd(&xbar[b * FDIM + tid],       s0 * (1.f / 2048.f));
    atomicAdd(&xbar[b * FDIM + tid + 256], s1 * (1.f / 2048.f));
}

__global__ __launch_bounds__(256) void metric_kernel(const float* __restrict__ xbar,
                                                     const float* __restrict__ Wk,
                                                     float* __restrict__ metric) {
    const int o = blockIdx.x * 256 + threadIdx.x;   // 2048 outputs
    const int b = o >> 9, f = o & 511;
    const float* xb = xbar + b * FDIM;
    const float* wr = Wk + (size_t)f * FDIM;
    float acc = 0.f;
#pragma unroll 4
    for (int kk = 0; kk < FDIM; kk += 4) {
        float4 wv = *(const float4*)(wr + kk);
        acc += xb[kk + 0] * wv.x + xb[kk + 1] * wv.y
             + xb[kk + 2] * wv.z + xb[kk + 3] * wv.w;
    }
    metric[o] = acc;
}

// ---------------------------------------------------------------------------
extern "C" void kernel_launch(void* const* d_in, const int* in_sizes, int n_in,
                              void* d_out, int out_size, void* d_ws, size_t ws_size,
                              hipStream_t stream) {
    const float* x      = (const float*)d_in[0];
    const float* coords = (const float*)d_in[1];
    const float* Wq     = (const float*)d_in[2];
    const float* Wk     = (const float*)d_in[3];
    const float* Wv     = (const float*)d_in[4];
    float* out    = (float*)d_out;
    float* metric = out + (size_t)BATCH * SF;

    // ws: kv_b f32 (2*S*F = 8 MiB) | nn u16 (512 KiB) | xbar f32 (8 KiB) ~= 8.5 MiB
    float* kvws = (float*)d_ws;
    u16*   nn   = (u16*)((char*)d_ws + 2 * SF * sizeof(float));
    float* xbar = (float*)((char*)d_ws + 2 * SF * sizeof(float)
                                       + (size_t)BATCH * SEQ * KNN * sizeof(u16));

    knn_kernel<<<BATCH * SEQ, 64, 0, stream>>>(coords, nn);

    // q for all batches -> d_out (each attn block consumes only its own row)
    gemm_xwt<<<dim3(FDIM / 64, (BATCH * SEQ) / 64), 256, 0, stream>>>(x, Wq, out);

    hipMemsetAsync(xbar, 0, BATCH * FDIM * sizeof(float), stream);
    xbar_kernel<<<dim3(BATCH, 32), 256, 0, stream>>>(x, xbar);
    metric_kernel<<<(BATCH * NHEAD * HDIM) / 256, 256, 0, stream>>>(xbar, Wk, metric);

    for (int b = 0; b < BATCH; ++b) {
        const float* xb = x + (size_t)b * SF;
        gemm_xwt<<<dim3(FDIM / 64, SEQ / 64), 256, 0, stream>>>(xb, Wk, kvws);        // k_b
        gemm_xwt<<<dim3(FDIM / 64, SEQ / 64), 256, 0, stream>>>(xb, Wv, kvws + SF);   // v_b
        attn_kernel<<<SEQ, 512, 0, stream>>>(kvws, nn + (size_t)b * SEQ * KNN,
                                             out + (size_t)b * SF);
    }
}

// Round 7
// 347.050 us; speedup vs baseline: 1.6255x; 1.6255x over previous
//
#include <hip/hip_runtime.h>
#include <stdint.h>

#define BATCH 4
#define SEQ   2048
#define FDIM  512
#define NHEAD 8
#define HDIM  64
#define KNN   32

typedef unsigned int u32;
typedef unsigned long long u64;
typedef unsigned short u16;
typedef unsigned short bf16_t;

typedef __attribute__((ext_vector_type(8))) short short8;   // 8 bf16 = 4 VGPRs
typedef __attribute__((ext_vector_type(4))) float f32x4;

#define SF  ((size_t)SEQ * FDIM)            // 1,048,576 per-batch elements
#define BSF ((size_t)BATCH * SF)            // 4,194,304

__device__ __forceinline__ bf16_t f2bf(float f) {
    u32 x = __float_as_uint(f);
    return (bf16_t)((x + 0x7FFFu + ((x >> 16) & 1u)) >> 16);   // RNE
}
__device__ __forceinline__ float bf2f(bf16_t u) { return __uint_as_float(((u32)u) << 16); }
__device__ __forceinline__ void bf2x2(u32 p, float& a, float& b) {
    a = __uint_as_float(p << 16);          // element 2i (low u16)
    b = __uint_as_float(p & 0xFFFF0000u);  // element 2i+1 (high u16)
}

__device__ __forceinline__ u64 shfl_xor_u64(u64 v, int m) {
    int lo = __shfl_xor((int)(u32)v, m, 64);
    int hi = __shfl_xor((int)(u32)(v >> 32), m, 64);
    return (((u64)(u32)hi) << 32) | (u32)lo;
}
__device__ __forceinline__ u64 min_u64(u64 a, u64 b) { return a < b ? a : b; }

// ---------------------------------------------------------------------------
// Cast x / Wq / Wk / Wv (fp32) -> bf16, 8 elements/thread. grid.z selects.
// ---------------------------------------------------------------------------
__global__ __launch_bounds__(256) void cast_kernel(const float* __restrict__ x,
                                                   const float* __restrict__ wq,
                                                   const float* __restrict__ wk,
                                                   const float* __restrict__ wv,
                                                   bf16_t* __restrict__ xb,
                                                   bf16_t* __restrict__ wqb,
                                                   bf16_t* __restrict__ wkb,
                                                   bf16_t* __restrict__ wvb) {
    const int z = blockIdx.z;
    const float* src = (z == 0) ? x : (z == 1) ? wq : (z == 2) ? wk : wv;
    bf16_t* dst      = (z == 0) ? xb : (z == 1) ? wqb : (z == 2) ? wkb : wvb;
    const size_t cnt8 = (z == 0) ? (BSF / 8) : ((size_t)FDIM * FDIM / 8);
    size_t idx = (size_t)blockIdx.x * 256 + threadIdx.x;
    if (idx >= cnt8) return;
    const float4 a = ((const float4*)src)[idx * 2 + 0];
    const float4 b = ((const float4*)src)[idx * 2 + 1];
    uint4 o;
    o.x = (u32)f2bf(a.x) | ((u32)f2bf(a.y) << 16);
    o.y = (u32)f2bf(a.z) | ((u32)f2bf(a.w) << 16);
    o.z = (u32)f2bf(b.x) | ((u32)f2bf(b.y) << 16);
    o.w = (u32)f2bf(b.z) | ((u32)f2bf(b.w) << 16);
    ((uint4*)dst)[idx] = o;
}

// ---------------------------------------------------------------------------
// kNN: one wave per query, fp32 coords. Stable-argsort emulation (self at
// rank 0, dropped). Key = (dist_bits<<32)|idx. LDS lists split u32/u16
// (12.5 KB vs 16.9 KB -> 13 blocks/CU vs 9).
// ---------------------------------------------------------------------------
__global__ __launch_bounds__(64) void knn_kernel(const float* __restrict__ coords,
                                                 u16* __restrict__ nn_out) {
    __shared__ u32 listsd[32 * 64];   // dist bits, [pos][lane]
    __shared__ u16 listsi[32 * 64];   // idx
    __shared__ u32 outbuf[KNN + 1];
    const int blk  = blockIdx.x;          // b*SEQ + qi
    const int b    = blk >> 11;
    const int qi   = blk & (SEQ - 1);
    const int lane = threadIdx.x;

    const float* cb = coords + (size_t)b * SEQ * 3;
    const float qx = cb[qi * 3 + 0];
    const float qy = cb[qi * 3 + 1];
    const float qz = cb[qi * 3 + 2];

    u64 key[32];
#pragma unroll
    for (int i = 0; i < 32; ++i) {
        int c = i * 64 + lane;
        float dx = __fsub_rn(cb[c * 3 + 0], qx);
        float dy = __fsub_rn(cb[c * 3 + 1], qy);
        float dz = __fsub_rn(cb[c * 3 + 2], qz);
        // numpy order: (dx*dx + dy*dy) + dz*dz, no FMA contraction, IEEE sqrt
        float d2 = __fadd_rn(__fadd_rn(__fmul_rn(dx, dx), __fmul_rn(dy, dy)),
                             __fmul_rn(dz, dz));
        float dist = __fsqrt_rn(d2);
        key[i] = (((u64)__float_as_uint(dist)) << 32) | (u32)c;   // self included
    }

    // per-lane bitonic sort, ascending, fully unrolled
#pragma unroll
    for (int k = 2; k <= 32; k <<= 1) {
#pragma unroll
        for (int j = k >> 1; j > 0; j >>= 1) {
#pragma unroll
            for (int i = 0; i < 32; ++i) {
                int ixj = i ^ j;
                if (ixj > i) {
                    bool up = (i & k) == 0;
                    u64 a = key[i], c2 = key[ixj];
                    bool sw = up ? (a > c2) : (a < c2);
                    u64 lo = sw ? c2 : a;
                    u64 hi = sw ? a : c2;
                    key[i] = lo;
                    key[ixj] = hi;
                }
            }
        }
    }

#pragma unroll
    for (int i = 0; i < 32; ++i) {
        listsd[i * 64 + lane] = (u32)(key[i] >> 32);
        listsi[i * 64 + lane] = (u16)key[i];
    }
    __syncthreads();

    u64 h = key[0];
    int ptr = 1;
#pragma unroll 1
    for (int r = 0; r < KNN + 1; ++r) {      // 33 winners; rank 0 = self slot
        u64 g = h;
        g = min_u64(g, shfl_xor_u64(g, 1));
        g = min_u64(g, shfl_xor_u64(g, 2));
        g = min_u64(g, shfl_xor_u64(g, 4));
        g = min_u64(g, shfl_xor_u64(g, 8));
        g = min_u64(g, shfl_xor_u64(g, 16));
        g = min_u64(g, shfl_xor_u64(g, 32));
        if (lane == 0) outbuf[r] = (u32)g;
        if (h == g) {                        // unique winner (idx embedded)
            h = (ptr < 32) ? ((((u64)listsd[ptr * 64 + lane]) << 32)
                             | listsi[ptr * 64 + lane])
                           : ~0ull;
            ++ptr;
        }
    }
    __syncthreads();
    if (lane < KNN) nn_out[(size_t)blk * KNN + lane] = (u16)(outbuf[lane + 1] & 0x7FF);
}

// ---------------------------------------------------------------------------
// MFMA projection GEMM: out[m,n] = sum_k A[m,k]*W[n,k]  (A @ W^T).
// bf16 inputs, fp32 acc. Direct global->register fragments (no LDS).
// Block 256 = 4 waves; block tile 64(M)x64(N); wave tile 16x64.
// Fragment layouts (m89/m91-verified):
//   A: a[j]   = A[m0w + (lane&15)][k0 + (lane>>4)*8 + j]
//   B: b[j]   = W[n0t + (lane&15)][k0 + (lane>>4)*8 + j]   (W row-major N x K)
//   D: reg r -> row = (lane>>4)*4 + r (M), col = lane&15 (N)
// z=0 -> q (fp32 into d_out); z=1 -> k, z=2 -> v (bf16 into ws kv).
// ---------------------------------------------------------------------------
__global__ __launch_bounds__(256) void gemm_mfma(const bf16_t* __restrict__ xb,
                                                 const bf16_t* __restrict__ wqb,
                                                 const bf16_t* __restrict__ wkb,
                                                 const bf16_t* __restrict__ wvb,
                                                 float* __restrict__ qout,
                                                 bf16_t* __restrict__ kvout) {
    const int z = blockIdx.z;
    const bf16_t* W = (z == 0) ? wqb : (z == 1) ? wkb : wvb;
    const int tid  = threadIdx.x;
    const int wid  = tid >> 6, lane = tid & 63;
    const int m16  = lane & 15, quad = lane >> 4;
    const int m0w  = blockIdx.y * 64 + wid * 16;
    const int n0   = blockIdx.x * 64;

    const bf16_t* ap = xb + (size_t)(m0w + m16) * FDIM + quad * 8;
    const bf16_t* bp0 = W + (size_t)(n0 +  0 + m16) * FDIM + quad * 8;
    const bf16_t* bp1 = W + (size_t)(n0 + 16 + m16) * FDIM + quad * 8;
    const bf16_t* bp2 = W + (size_t)(n0 + 32 + m16) * FDIM + quad * 8;
    const bf16_t* bp3 = W + (size_t)(n0 + 48 + m16) * FDIM + quad * 8;

    f32x4 acc0 = {0.f, 0.f, 0.f, 0.f}, acc1 = acc0, acc2 = acc0, acc3 = acc0;

#pragma unroll
    for (int k = 0; k < FDIM; k += 32) {
        short8 a  = *(const short8*)(ap  + k);
        short8 b0 = *(const short8*)(bp0 + k);
        short8 b1 = *(const short8*)(bp1 + k);
        short8 b2 = *(const short8*)(bp2 + k);
        short8 b3 = *(const short8*)(bp3 + k);
        acc0 = __builtin_amdgcn_mfma_f32_16x16x32_bf16(a, b0, acc0, 0, 0, 0);
        acc1 = __builtin_amdgcn_mfma_f32_16x16x32_bf16(a, b1, acc1, 0, 0, 0);
        acc2 = __builtin_amdgcn_mfma_f32_16x16x32_bf16(a, b2, acc2, 0, 0, 0);
        acc3 = __builtin_amdgcn_mfma_f32_16x16x32_bf16(a, b3, acc3, 0, 0, 0);
    }

    const int rowb = m0w + quad * 4;
    if (z == 0) {
#pragma unroll
        for (int r = 0; r < 4; ++r) {
            float* orow = qout + (size_t)(rowb + r) * FDIM + n0 + m16;
            orow[ 0] = acc0[r]; orow[16] = acc1[r];
            orow[32] = acc2[r]; orow[48] = acc3[r];
        }
    } else {
        bf16_t* base = kvout + (size_t)(z - 1) * BSF;
#pragma unroll
        for (int r = 0; r < 4; ++r) {
            bf16_t* orow = base + (size_t)(rowb + r) * FDIM + n0 + m16;
            orow[ 0] = f2bf(acc0[r]); orow[16] = f2bf(acc1[r]);
            orow[32] = f2bf(acc2[r]); orow[48] = f2bf(acc3[r]);
        }
    }
}

// ---------------------------------------------------------------------------
// Attention, ALL batches: block per (b,q), 512 thr = 8 waves, wave per head.
// kv bf16 = [k_all | v_all] in ws. q read fp32 from d_out (own row), then
// overwritten with the result.
// ---------------------------------------------------------------------------
__global__ __launch_bounds__(512) void attn_kernel(const bf16_t* __restrict__ kv,
                                                   const u16* __restrict__ nn,
                                                   float* __restrict__ out) {
    __shared__ float qs[FDIM];
    __shared__ int   sidx[KNN];
    __shared__ float wls[NHEAD][KNN];
    const int blk = blockIdx.x;            // b*SEQ + q
    const int b   = blk >> 11;
    const int tid = threadIdx.x;
    const int h = tid >> 6, lane = tid & 63;

    qs[tid] = out[(size_t)blk * FDIM + tid];                  // own q row
    if (tid < KNN) sidx[tid] = (int)nn[(size_t)blk * KNN + tid] & (SEQ - 1);
    __syncthreads();

    const int j = lane & 31, half = lane >> 5;
    const bf16_t* kreg = kv + ((size_t)((b << 11) + sidx[j])) * FDIM + h * HDIM + half * 32;
    const float* qp = &qs[h * HDIM + half * 32];
    float acc = 0.f;
#pragma unroll
    for (int d = 0; d < 32; d += 8) {
        uint4 kvv = *(const uint4*)(kreg + d);   // 8 bf16
        float f0, f1, f2, f3, f4, f5, f6, f7;
        bf2x2(kvv.x, f0, f1); bf2x2(kvv.y, f2, f3);
        bf2x2(kvv.z, f4, f5); bf2x2(kvv.w, f6, f7);
        acc += qp[d + 0] * f0 + qp[d + 1] * f1 + qp[d + 2] * f2 + qp[d + 3] * f3
             + qp[d + 4] * f4 + qp[d + 5] * f5 + qp[d + 6] * f6 + qp[d + 7] * f7;
    }
    acc += __shfl_xor(acc, 32, 64);
    float s = acc * 0.125f;                 // 1/sqrt(64)
    float m = s;
    m = fmaxf(m, __shfl_xor(m, 1, 64));
    m = fmaxf(m, __shfl_xor(m, 2, 64));
    m = fmaxf(m, __shfl_xor(m, 4, 64));
    m = fmaxf(m, __shfl_xor(m, 8, 64));
    m = fmaxf(m, __shfl_xor(m, 16, 64));
    float e = __expf(s - m);
    float sum = e;
    sum += __shfl_xor(sum, 1, 64);
    sum += __shfl_xor(sum, 2, 64);
    sum += __shfl_xor(sum, 4, 64);
    sum += __shfl_xor(sum, 8, 64);
    sum += __shfl_xor(sum, 16, 64);
    float w = e / sum;
    if (half == 0) wls[h][j] = w;
    __syncthreads();

    const bf16_t* vb = kv + BSF + ((size_t)(b << 11)) * FDIM + h * HDIM + lane;
    float o = 0.f;
#pragma unroll 4
    for (int j2 = 0; j2 < KNN; ++j2) {
        o += wls[h][j2] * bf2f(vb[(size_t)sidx[j2] * FDIM]);
    }
    out[(size_t)blk * FDIM + h * HDIM + lane] = o;
}

// ---------------------------------------------------------------------------
// metric = mean_s(k) = (mean_s x) @ Wk^T  (linearity), fp32 from raw inputs
// ---------------------------------------------------------------------------
__global__ __launch_bounds__(256) void xbar_kernel(const float* __restrict__ x,
                                                   float* __restrict__ xbar) {
    const int b = blockIdx.x, chunk = blockIdx.y;   // 32 chunks of 64 rows
    const int tid = threadIdx.x;
    const float* xp = x + (size_t)b * SF + (size_t)chunk * 64 * FDIM;
    float s0 = 0.f, s1 = 0.f;
    for (int r = 0; r < 64; ++r) {
        s0 += xp[(size_t)r * FDIM + tid];
        s1 += xp[(size_t)r * FDIM + tid + 256];
    }
    atomicAdd(&xbar[b * FDIM + tid],       s0 * (1.f / 2048.f));
    atomicAdd(&xbar[b * FDIM + tid + 256], s1 * (1.f / 2048.f));
}

__global__ __launch_bounds__(256) void metric_kernel(const float* __restrict__ xbar,
                                                     const float* __restrict__ Wk,
                                                     float* __restrict__ metric) {
    const int o = blockIdx.x * 256 + threadIdx.x;   // 2048 outputs
    const int b = o >> 9, f = o & 511;
    const float* xb = xbar + b * FDIM;
    const float* wr = Wk + (size_t)f * FDIM;
    float acc = 0.f;
#pragma unroll 4
    for (int kk = 0; kk < FDIM; kk += 4) {
        float4 wv = *(const float4*)(wr + kk);
        acc += xb[kk + 0] * wv.x + xb[kk + 1] * wv.y
             + xb[kk + 2] * wv.z + xb[kk + 3] * wv.w;
    }
    metric[o] = acc;
}

// ---------------------------------------------------------------------------
extern "C" void kernel_launch(void* const* d_in, const int* in_sizes, int n_in,
                              void* d_out, int out_size, void* d_ws, size_t ws_size,
                              hipStream_t stream) {
    const float* x      = (const float*)d_in[0];
    const float* coords = (const float*)d_in[1];
    const float* Wq     = (const float*)d_in[2];
    const float* Wk     = (const float*)d_in[3];
    const float* Wv     = (const float*)d_in[4];
    float* out    = (float*)d_out;
    float* metric = out + BSF;

    // ws layout (26.0 MiB):
    //   xb   bf16  BSF            =  8 MiB
    //   wqb/wkb/wvb bf16 3*512KiB = 1.5 MiB
    //   kv   bf16  2*BSF          = 16 MiB
    //   nn   u16   B*S*K          = 0.5 MiB
    //   xbar f32   B*F            = 8 KiB
    char* p = (char*)d_ws;
    bf16_t* xb   = (bf16_t*)p;                       p += BSF * sizeof(bf16_t);
    bf16_t* wqb  = (bf16_t*)p;                       p += (size_t)FDIM * FDIM * sizeof(bf16_t);
    bf16_t* wkb  = (bf16_t*)p;                       p += (size_t)FDIM * FDIM * sizeof(bf16_t);
    bf16_t* wvb  = (bf16_t*)p;                       p += (size_t)FDIM * FDIM * sizeof(bf16_t);
    bf16_t* kv   = (bf16_t*)p;                       p += 2 * BSF * sizeof(bf16_t);
    u16*    nn   = (u16*)p;                          p += (size_t)BATCH * SEQ * KNN * sizeof(u16);
    float*  xbar = (float*)p;

    cast_kernel<<<dim3(BSF / 8 / 256, 1, 4), 256, 0, stream>>>(x, Wq, Wk, Wv,
                                                               xb, wqb, wkb, wvb);
    knn_kernel<<<BATCH * SEQ, 64, 0, stream>>>(coords, nn);

    // q -> d_out (fp32), k/v -> ws (bf16); one dispatch
    gemm_mfma<<<dim3(FDIM / 64, (BATCH * SEQ) / 64, 3), 256, 0, stream>>>(
        xb, wqb, wkb, wvb, out, kv);

    hipMemsetAsync(xbar, 0, BATCH * FDIM * sizeof(float), stream);
    xbar_kernel<<<dim3(BATCH, 32), 256, 0, stream>>>(x, xbar);
    metric_kernel<<<(BATCH * NHEAD * HDIM) / 256, 256, 0, stream>>>(xbar, Wk, metric);

    attn_kernel<<<BATCH * SEQ, 512, 0, stream>>>(kv, nn, out);
}

// Round 8
// 261.057 us; speedup vs baseline: 2.1609x; 1.3294x over previous
//
#include <hip/hip_runtime.h>
#include <stdint.h>

#define BATCH 4
#define SEQ   2048
#define FDIM  512
#define NHEAD 8
#define HDIM  64
#define KNN   32

typedef unsigned int u32;
typedef unsigned long long u64;
typedef unsigned short u16;
typedef unsigned short bf16_t;

typedef __attribute__((ext_vector_type(8))) short short8;   // 8 bf16 = 4 VGPRs
typedef __attribute__((ext_vector_type(4))) float f32x4;

#define SF  ((size_t)SEQ * FDIM)            // 1,048,576 per-batch elements
#define BSF ((size_t)BATCH * SF)            // 4,194,304

__device__ __forceinline__ bf16_t f2bf(float f) {
    u32 x = __float_as_uint(f);
    return (bf16_t)((x + 0x7FFFu + ((x >> 16) & 1u)) >> 16);   // RNE
}
__device__ __forceinline__ float bf2f(bf16_t u) { return __uint_as_float(((u32)u) << 16); }
__device__ __forceinline__ void bf2x2(u32 p, float& a, float& b) {
    a = __uint_as_float(p << 16);          // element 2i (low u16)
    b = __uint_as_float(p & 0xFFFF0000u);  // element 2i+1 (high u16)
}

__device__ __forceinline__ u64 shfl_xor_u64(u64 v, int m) {
    int lo = __shfl_xor((int)(u32)v, m, 64);
    int hi = __shfl_xor((int)(u32)(v >> 32), m, 64);
    return (((u64)(u32)hi) << 32) | (u32)lo;
}
__device__ __forceinline__ u64 min_u64(u64 a, u64 b) { return a < b ? a : b; }

// ---------------------------------------------------------------------------
// Cast x / Wq / Wk / Wv (fp32) -> bf16, 8 elements/thread. grid.z selects.
// ---------------------------------------------------------------------------
__global__ __launch_bounds__(256) void cast_kernel(const float* __restrict__ x,
                                                   const float* __restrict__ wq,
                                                   const float* __restrict__ wk,
                                                   const float* __restrict__ wv,
                                                   bf16_t* __restrict__ xb,
                                                   bf16_t* __restrict__ wqb,
                                                   bf16_t* __restrict__ wkb,
                                                   bf16_t* __restrict__ wvb) {
    const int z = blockIdx.z;
    const float* src = (z == 0) ? x : (z == 1) ? wq : (z == 2) ? wk : wv;
    bf16_t* dst      = (z == 0) ? xb : (z == 1) ? wqb : (z == 2) ? wkb : wvb;
    const size_t cnt8 = (z == 0) ? (BSF / 8) : ((size_t)FDIM * FDIM / 8);
    size_t idx = (size_t)blockIdx.x * 256 + threadIdx.x;
    if (idx >= cnt8) return;
    const float4 a = ((const float4*)src)[idx * 2 + 0];
    const float4 b = ((const float4*)src)[idx * 2 + 1];
    uint4 o;
    o.x = (u32)f2bf(a.x) | ((u32)f2bf(a.y) << 16);
    o.y = (u32)f2bf(a.z) | ((u32)f2bf(a.w) << 16);
    o.z = (u32)f2bf(b.x) | ((u32)f2bf(b.y) << 16);
    o.w = (u32)f2bf(b.z) | ((u32)f2bf(b.w) << 16);
    ((uint4*)dst)[idx] = o;
}

// ---------------------------------------------------------------------------
// kNN: one wave per query, fp32 coords. Stable-argsort emulation (self at
// rank 0, dropped). Key = (dist_bits<<32)|idx.
// ---------------------------------------------------------------------------
__global__ __launch_bounds__(64) void knn_kernel(const float* __restrict__ coords,
                                                 u16* __restrict__ nn_out) {
    __shared__ u32 listsd[32 * 64];   // dist bits, [pos][lane]
    __shared__ u16 listsi[32 * 64];   // idx
    __shared__ u32 outbuf[KNN + 1];
    const int blk  = blockIdx.x;          // b*SEQ + qi
    const int b    = blk >> 11;
    const int qi   = blk & (SEQ - 1);
    const int lane = threadIdx.x;

    const float* cb = coords + (size_t)b * SEQ * 3;
    const float qx = cb[qi * 3 + 0];
    const float qy = cb[qi * 3 + 1];
    const float qz = cb[qi * 3 + 2];

    u64 key[32];
#pragma unroll
    for (int i = 0; i < 32; ++i) {
        int c = i * 64 + lane;
        float dx = __fsub_rn(cb[c * 3 + 0], qx);
        float dy = __fsub_rn(cb[c * 3 + 1], qy);
        float dz = __fsub_rn(cb[c * 3 + 2], qz);
        // numpy order: (dx*dx + dy*dy) + dz*dz, no FMA contraction, IEEE sqrt
        float d2 = __fadd_rn(__fadd_rn(__fmul_rn(dx, dx), __fmul_rn(dy, dy)),
                             __fmul_rn(dz, dz));
        float dist = __fsqrt_rn(d2);
        key[i] = (((u64)__float_as_uint(dist)) << 32) | (u32)c;   // self included
    }

    // per-lane bitonic sort, ascending, fully unrolled
#pragma unroll
    for (int k = 2; k <= 32; k <<= 1) {
#pragma unroll
        for (int j = k >> 1; j > 0; j >>= 1) {
#pragma unroll
            for (int i = 0; i < 32; ++i) {
                int ixj = i ^ j;
                if (ixj > i) {
                    bool up = (i & k) == 0;
                    u64 a = key[i], c2 = key[ixj];
                    bool sw = up ? (a > c2) : (a < c2);
                    u64 lo = sw ? c2 : a;
                    u64 hi = sw ? a : c2;
                    key[i] = lo;
                    key[ixj] = hi;
                }
            }
        }
    }

#pragma unroll
    for (int i = 0; i < 32; ++i) {
        listsd[i * 64 + lane] = (u32)(key[i] >> 32);
        listsi[i * 64 + lane] = (u16)key[i];
    }
    __syncthreads();

    u64 h = key[0];
    int ptr = 1;
#pragma unroll 1
    for (int r = 0; r < KNN + 1; ++r) {      // 33 winners; rank 0 = self slot
        u64 g = h;
        g = min_u64(g, shfl_xor_u64(g, 1));
        g = min_u64(g, shfl_xor_u64(g, 2));
        g = min_u64(g, shfl_xor_u64(g, 4));
        g = min_u64(g, shfl_xor_u64(g, 8));
        g = min_u64(g, shfl_xor_u64(g, 16));
        g = min_u64(g, shfl_xor_u64(g, 32));
        if (lane == 0) outbuf[r] = (u32)g;
        if (h == g) {                        // unique winner (idx embedded)
            h = (ptr < 32) ? ((((u64)listsd[ptr * 64 + lane]) << 32)
                             | listsi[ptr * 64 + lane])
                           : ~0ull;
            ++ptr;
        }
    }
    __syncthreads();
    if (lane < KNN) nn_out[(size_t)blk * KNN + lane] = (u16)(outbuf[lane + 1] & 0x7FF);
}

// ---------------------------------------------------------------------------
// LDS-tiled MFMA GEMM (m93 structure): out[m,n] = sum_k A[m,k]*W[n,k].
// 128x128 block tile, BK=32, 256 thr = 4 waves (2x2), 64x64 wave tile,
// 4x4 grid of 16x16x32 MFMAs, fp32 acc. VGPR-staged LDS (16 KB).
// Fragment + epilogue index math identical to the round-7 HW-validated kernel.
// z=0 -> q (fp32 to d_out); z=1,2 -> k,v (bf16 to ws).
// ---------------------------------------------------------------------------
__global__ __launch_bounds__(256) void gemm_mfma(const bf16_t* __restrict__ xb,
                                                 const bf16_t* __restrict__ wqb,
                                                 const bf16_t* __restrict__ wkb,
                                                 const bf16_t* __restrict__ wvb,
                                                 float* __restrict__ qout,
                                                 bf16_t* __restrict__ kvout) {
    __shared__ __align__(16) bf16_t As[128 * 32];
    __shared__ __align__(16) bf16_t Bs[128 * 32];
    const int z = blockIdx.z;
    const bf16_t* W = (z == 0) ? wqb : (z == 1) ? wkb : wvb;
    const int tid  = threadIdx.x;
    const int wid  = tid >> 6, lane = tid & 63;
    const int m16  = lane & 15, quad = lane >> 4;
    const int wm   = (wid & 1) * 64;          // wave M-offset in tile
    const int wn   = (wid >> 1) * 64;         // wave N-offset in tile
    const int m0   = blockIdx.y * 128;
    const int n0   = blockIdx.x * 128;

    // staging: thread t covers rows sr & sr+64, k-chunk sc (8 bf16 = 16 B)
    const int sr = tid >> 2, sc = (tid & 3) * 8;
    const bf16_t* agp = xb + (size_t)(m0 + sr) * FDIM + sc;
    const bf16_t* bgp = W  + (size_t)(n0 + sr) * FDIM + sc;

    f32x4 acc[4][4];
#pragma unroll
    for (int i = 0; i < 4; ++i)
#pragma unroll
        for (int j = 0; j < 4; ++j) acc[i][j] = (f32x4){0.f, 0.f, 0.f, 0.f};

#pragma unroll 1
    for (int k0 = 0; k0 < FDIM; k0 += 32) {
        uint4 a0 = *(const uint4*)(agp + k0);
        uint4 a1 = *(const uint4*)(agp + (size_t)64 * FDIM + k0);
        uint4 b0 = *(const uint4*)(bgp + k0);
        uint4 b1 = *(const uint4*)(bgp + (size_t)64 * FDIM + k0);
        __syncthreads();                       // previous tile fully consumed
        *(uint4*)(As + sr * 32 + sc)        = a0;
        *(uint4*)(As + (sr + 64) * 32 + sc) = a1;
        *(uint4*)(Bs + sr * 32 + sc)        = b0;
        *(uint4*)(Bs + (sr + 64) * 32 + sc) = b1;
        __syncthreads();                       // tile visible to all waves

        short8 af[4], bfr[4];
#pragma unroll
        for (int i = 0; i < 4; ++i)
            af[i] = *(const short8*)(As + (wm + i * 16 + m16) * 32 + quad * 8);
#pragma unroll
        for (int j = 0; j < 4; ++j)
            bfr[j] = *(const short8*)(Bs + (wn + j * 16 + m16) * 32 + quad * 8);
#pragma unroll
        for (int i = 0; i < 4; ++i)
#pragma unroll
            for (int j = 0; j < 4; ++j)
                acc[i][j] = __builtin_amdgcn_mfma_f32_16x16x32_bf16(af[i], bfr[j],
                                                                    acc[i][j], 0, 0, 0);
    }

    // epilogue: D reg r -> row quad*4+r, col m16 (HW-validated in round 7)
    if (z == 0) {
#pragma unroll
        for (int i = 0; i < 4; ++i) {
            const int rowb = m0 + wm + i * 16 + quad * 4;
#pragma unroll
            for (int r = 0; r < 4; ++r) {
                float* orow = qout + (size_t)(rowb + r) * FDIM + n0 + wn + m16;
                orow[ 0] = acc[i][0][r]; orow[16] = acc[i][1][r];
                orow[32] = acc[i][2][r]; orow[48] = acc[i][3][r];
            }
        }
    } else {
        bf16_t* base = kvout + (size_t)(z - 1) * BSF;
#pragma unroll
        for (int i = 0; i < 4; ++i) {
            const int rowb = m0 + wm + i * 16 + quad * 4;
#pragma unroll
            for (int r = 0; r < 4; ++r) {
                bf16_t* orow = base + (size_t)(rowb + r) * FDIM + n0 + wn + m16;
                orow[ 0] = f2bf(acc[i][0][r]); orow[16] = f2bf(acc[i][1][r]);
                orow[32] = f2bf(acc[i][2][r]); orow[48] = f2bf(acc[i][3][r]);
            }
        }
    }
}

// ---------------------------------------------------------------------------
// Attention, ALL batches: block per (b,q), 512 thr = 8 waves, wave per head.
// kv bf16 = [k_all | v_all] in ws. q read fp32 from d_out (own row), then
// overwritten with the result.
// ---------------------------------------------------------------------------
__global__ __launch_bounds__(512) void attn_kernel(const bf16_t* __restrict__ kv,
                                                   const u16* __restrict__ nn,
                                                   float* __restrict__ out) {
    __shared__ float qs[FDIM];
    __shared__ int   sidx[KNN];
    __shared__ float wls[NHEAD][KNN];
    const int blk = blockIdx.x;            // b*SEQ + q
    const int b   = blk >> 11;
    const int tid = threadIdx.x;
    const int h = tid >> 6, lane = tid & 63;

    qs[tid] = out[(size_t)blk * FDIM + tid];                  // own q row
    if (tid < KNN) sidx[tid] = (int)nn[(size_t)blk * KNN + tid] & (SEQ - 1);
    __syncthreads();

    const int j = lane & 31, half = lane >> 5;
    const bf16_t* kreg = kv + ((size_t)((b << 11) + sidx[j])) * FDIM + h * HDIM + half * 32;
    const float* qp = &qs[h * HDIM + half * 32];
    float acc = 0.f;
#pragma unroll
    for (int d = 0; d < 32; d += 8) {
        uint4 kvv = *(const uint4*)(kreg + d);   // 8 bf16
        float f0, f1, f2, f3, f4, f5, f6, f7;
        bf2x2(kvv.x, f0, f1); bf2x2(kvv.y, f2, f3);
        bf2x2(kvv.z, f4, f5); bf2x2(kvv.w, f6, f7);
        acc += qp[d + 0] * f0 + qp[d + 1] * f1 + qp[d + 2] * f2 + qp[d + 3] * f3
             + qp[d + 4] * f4 + qp[d + 5] * f5 + qp[d + 6] * f6 + qp[d + 7] * f7;
    }
    acc += __shfl_xor(acc, 32, 64);
    float s = acc * 0.125f;                 // 1/sqrt(64)
    float m = s;
    m = fmaxf(m, __shfl_xor(m, 1, 64));
    m = fmaxf(m, __shfl_xor(m, 2, 64));
    m = fmaxf(m, __shfl_xor(m, 4, 64));
    m = fmaxf(m, __shfl_xor(m, 8, 64));
    m = fmaxf(m, __shfl_xor(m, 16, 64));
    float e = __expf(s - m);
    float sum = e;
    sum += __shfl_xor(sum, 1, 64);
    sum += __shfl_xor(sum, 2, 64);
    sum += __shfl_xor(sum, 4, 64);
    sum += __shfl_xor(sum, 8, 64);
    sum += __shfl_xor(sum, 16, 64);
    float w = e / sum;
    if (half == 0) wls[h][j] = w;
    __syncthreads();

    const bf16_t* vb = kv + BSF + ((size_t)(b << 11)) * FDIM + h * HDIM + lane;
    float o = 0.f;
#pragma unroll 4
    for (int j2 = 0; j2 < KNN; ++j2) {
        o += wls[h][j2] * bf2f(vb[(size_t)sidx[j2] * FDIM]);
    }
    out[(size_t)blk * FDIM + h * HDIM + lane] = o;
}

// ---------------------------------------------------------------------------
// metric = mean_s(k) = (mean_s x) @ Wk^T  (linearity), fp32 from raw inputs
// ---------------------------------------------------------------------------
__global__ __launch_bounds__(256) void xbar_kernel(const float* __restrict__ x,
                                                   float* __restrict__ xbar) {
    const int b = blockIdx.x, chunk = blockIdx.y;   // 32 chunks of 64 rows
    const int tid = threadIdx.x;
    const float* xp = x + (size_t)b * SF + (size_t)chunk * 64 * FDIM;
    float s0 = 0.f, s1 = 0.f;
    for (int r = 0; r < 64; ++r) {
        s0 += xp[(size_t)r * FDIM + tid];
        s1 += xp[(size_t)r * FDIM + tid + 256];
    }
    atomicAdd(&xbar[b * FDIM + tid],       s0 * (1.f / 2048.f));
    atomicAdd(&xbar[b * FDIM + tid + 256], s1 * (1.f / 2048.f));
}

__global__ __launch_bounds__(256) void metric_kernel(const float* __restrict__ xbar,
                                                     const float* __restrict__ Wk,
                                                     float* __restrict__ metric) {
    const int o = blockIdx.x * 256 + threadIdx.x;   // 2048 outputs
    const int b = o >> 9, f = o & 511;
    const float* xb = xbar + b * FDIM;
    const float* wr = Wk + (size_t)f * FDIM;
    float acc = 0.f;
#pragma unroll 4
    for (int kk = 0; kk < FDIM; kk += 4) {
        float4 wv = *(const float4*)(wr + kk);
        acc += xb[kk + 0] * wv.x + xb[kk + 1] * wv.y
             + xb[kk + 2] * wv.z + xb[kk + 3] * wv.w;
    }
    metric[o] = acc;
}

// ---------------------------------------------------------------------------
extern "C" void kernel_launch(void* const* d_in, const int* in_sizes, int n_in,
                              void* d_out, int out_size, void* d_ws, size_t ws_size,
                              hipStream_t stream) {
    const float* x      = (const float*)d_in[0];
    const float* coords = (const float*)d_in[1];
    const float* Wq     = (const float*)d_in[2];
    const float* Wk     = (const float*)d_in[3];
    const float* Wv     = (const float*)d_in[4];
    float* out    = (float*)d_out;
    float* metric = out + BSF;

    // ws layout (26.0 MiB):
    //   xb bf16 BSF (8 MiB) | wqb/wkb/wvb bf16 (1.5 MiB) | kv bf16 2*BSF (16 MiB)
    //   | nn u16 (0.5 MiB) | xbar f32 (8 KiB)
    char* p = (char*)d_ws;
    bf16_t* xb   = (bf16_t*)p;                       p += BSF * sizeof(bf16_t);
    bf16_t* wqb  = (bf16_t*)p;                       p += (size_t)FDIM * FDIM * sizeof(bf16_t);
    bf16_t* wkb  = (bf16_t*)p;                       p += (size_t)FDIM * FDIM * sizeof(bf16_t);
    bf16_t* wvb  = (bf16_t*)p;                       p += (size_t)FDIM * FDIM * sizeof(bf16_t);
    bf16_t* kv   = (bf16_t*)p;                       p += 2 * BSF * sizeof(bf16_t);
    u16*    nn   = (u16*)p;                          p += (size_t)BATCH * SEQ * KNN * sizeof(u16);
    float*  xbar = (float*)p;

    cast_kernel<<<dim3(BSF / 8 / 256, 1, 4), 256, 0, stream>>>(x, Wq, Wk, Wv,
                                                               xb, wqb, wkb, wvb);
    knn_kernel<<<BATCH * SEQ, 64, 0, stream>>>(coords, nn);

    // q -> d_out (fp32), k/v -> ws (bf16); one dispatch, 128x128 tiles
    gemm_mfma<<<dim3(FDIM / 128, (BATCH * SEQ) / 128, 3), 256, 0, stream>>>(
        xb, wqb, wkb, wvb, out, kv);

    hipMemsetAsync(xbar, 0, BATCH * FDIM * sizeof(float), stream);
    xbar_kernel<<<dim3(BATCH, 32), 256, 0, stream>>>(x, xbar);
    metric_kernel<<<(BATCH * NHEAD * HDIM) / 256, 256, 0, stream>>>(xbar, Wk, metric);

    attn_kernel<<<BATCH * SEQ, 512, 0, stream>>>(kv, nn, out);
}